// Round 7
// baseline (659.738 us; speedup 1.0000x reference)
//
#include <hip/hip_runtime.h>
#include <hip/hip_cooperative_groups.h>
#include <math.h>

namespace cg = cooperative_groups;

#define NSTATE 65536          // 2^16
#define OUTSTRIDE 131328      // 2*65536 + 256

// ============================================================================
// R6 lesson: the 6-dispatch pipeline averaged ~27us/dispatch vs ~10us ideal --
// launch/drain serialization dominates. This round: ONE cooperative kernel
// (256 blocks x 1024 threads, 1 block/CU), grid.sync() between phases, coefs
// LDS-resident, and layer-0's product state evaluated in CLOSED FORM (kills
// one full state round-trip: 4 gate phases -> 3, 2 gathers).
//   Phase A: amp = d_om * prod_q Rq(0)[bit_q][0]  (d = row om, col 0 of
//            [R01(1) E01(0) R012(0)]);  locals E2-14(0), R3-15(1) -> real
//   Phase B: gather [R2(1) E01(1) R01(2)] from real; E2-14(1), R3-15(2) -> imag
//   Phase C: gather [R2(2) E01(2)] from imag; E2-14(2) -> real (final)
//   Tail   : zero imag.
// Amp index A: bits 0-2 = om (block octant), 3-8 = lane, 9-12 = wave,
// 13-15 = j slot (v0.xyzw,v1.xyzw). b = bid&31 keeps a batch's 8 octant
// blocks on one XCD (SPX round-robin) for L2-local gathers.
// ============================================================================

// ---- boundary-row builders (row om of composite 8x8; reverse-chron apply) ----
#define RP(A,B) { float t=A; A = t*g00 + B*g10; B = B*g11 + t*g01; }
#define RB0 RP(r0,r1) RP(r2,r3) RP(r4,r5) RP(r6,r7)
#define RB1 RP(r0,r2) RP(r1,r3) RP(r4,r6) RP(r5,r7)
#define RB2 RP(r0,r4) RP(r1,r5) RP(r2,r6) RP(r3,r7)
#define RRB(l,q,BITS) { const float* gg = sc + ((l)*16+(q))*4; \
  const float g00=gg[0], g01=gg[1], g10=gg[2], g11=gg[3]; BITS }
#define EP(A,B) { float t=A; A = (1.f-p)*A + p*B; B = (1.f-p)*B + p*t; }
#define REB0(l) { const float p = sc[192+(l)*15+0]; EP(r1,r3) EP(r5,r7) }   // ent0: ctrl b0, tgt b1
#define REB1(l) { const float p = sc[192+(l)*15+1]; EP(r2,r6) EP(r3,r7) }   // ent1: ctrl b1, tgt b2
#define ROWINIT r0=(om==0)?1.f:0.f; r1=(om==1)?1.f:0.f; r2=(om==2)?1.f:0.f; \
  r3=(om==3)?1.f:0.f; r4=(om==4)?1.f:0.f; r5=(om==5)?1.f:0.f; \
  r6=(om==6)?1.f:0.f; r7=(om==7)?1.f:0.f;

// ---- local gates (state in v0,v1; sc/xbuf/lane/wv/om/tid in scope) ----
#define SH4(v) { float ox=__shfl_xor(v.x,msk,64), oy=__shfl_xor(v.y,msk,64), \
                       oz=__shfl_xor(v.z,msk,64), ow=__shfl_xor(v.w,msk,64); \
  v.x=cown*v.x+coth*ox; v.y=cown*v.y+coth*oy; v.z=cown*v.z+coth*oz; v.w=cown*v.w+coth*ow; }
#define ROTL(l,q) { const float* gg = sc + ((l)*16+(q))*4; \
  const float g00=gg[0], g01=gg[1], g10=gg[2], g11=gg[3]; \
  const int msk = 1<<((q)-3); const int lb = (lane>>((q)-3))&1; \
  const float cown = lb?g11:g00, coth = lb?g10:g01; SH4(v0) SH4(v1) }
#define ROTW(l,q) { const float* gg = sc + ((l)*16+(q))*4; \
  const float g00=gg[0], g01=gg[1], g10=gg[2], g11=gg[3]; \
  const int k=(q)-9; const int bt=(wv>>k)&1; \
  const float cown = bt?g11:g00, coth = bt?g10:g01; \
  const int pb = ((wv^(1<<k))<<6)|lane; \
  __syncthreads(); xbuf[tid]=v0; xbuf[1024+tid]=v1; __syncthreads(); \
  { float4 o=xbuf[pb];      v0.x=cown*v0.x+coth*o.x; v0.y=cown*v0.y+coth*o.y; \
                            v0.z=cown*v0.z+coth*o.z; v0.w=cown*v0.w+coth*o.w; } \
  { float4 o=xbuf[1024+pb]; v1.x=cown*v1.x+coth*o.x; v1.y=cown*v1.y+coth*o.y; \
                            v1.z=cown*v1.z+coth*o.z; v1.w=cown*v1.w+coth*o.w; } }
#define ROT13(l) { const float* gg = sc + ((l)*16+13)*4; \
  const float g00=gg[0], g01=gg[1], g10=gg[2], g11=gg[3]; float nx,ny,nz,nw; \
  nx=g00*v0.x+g01*v0.y; ny=g10*v0.x+g11*v0.y; nz=g00*v0.z+g01*v0.w; nw=g10*v0.z+g11*v0.w; \
  v0.x=nx; v0.y=ny; v0.z=nz; v0.w=nw; \
  nx=g00*v1.x+g01*v1.y; ny=g10*v1.x+g11*v1.y; nz=g00*v1.z+g01*v1.w; nw=g10*v1.z+g11*v1.w; \
  v1.x=nx; v1.y=ny; v1.z=nz; v1.w=nw; }
#define ROT14(l) { const float* gg = sc + ((l)*16+14)*4; \
  const float g00=gg[0], g01=gg[1], g10=gg[2], g11=gg[3]; float nx,ny,nz,nw; \
  nx=g00*v0.x+g01*v0.z; nz=g10*v0.x+g11*v0.z; ny=g00*v0.y+g01*v0.w; nw=g10*v0.y+g11*v0.w; \
  v0.x=nx; v0.y=ny; v0.z=nz; v0.w=nw; \
  nx=g00*v1.x+g01*v1.z; nz=g10*v1.x+g11*v1.z; ny=g00*v1.y+g01*v1.w; nw=g10*v1.y+g11*v1.w; \
  v1.x=nx; v1.y=ny; v1.z=nz; v1.w=nw; }
#define ROT15(l) { const float* gg = sc + ((l)*16+15)*4; \
  const float g00=gg[0], g01=gg[1], g10=gg[2], g11=gg[3]; float t; \
  t=v0.x; v0.x=g00*t+g01*v1.x; v1.x=g10*t+g11*v1.x; \
  t=v0.y; v0.y=g00*t+g01*v1.y; v1.y=g10*t+g11*v1.y; \
  t=v0.z; v0.z=g00*t+g01*v1.z; v1.z=g10*t+g11*v1.z; \
  t=v0.w; v0.w=g00*t+g01*v1.w; v1.w=g10*t+g11*v1.w; }

#define ESH(v) { float ox=__shfl_xor(v.x,msk,64), oy=__shfl_xor(v.y,msk,64), \
                       oz=__shfl_xor(v.z,msk,64), ow=__shfl_xor(v.w,msk,64); \
  v.x+=pe*(ox-v.x); v.y+=pe*(oy-v.y); v.z+=pe*(oz-v.z); v.w+=pe*(ow-v.w); }
#define ENT2(l) { const float p = sc[192+(l)*15+2]; const float pe = (om&4)?p:0.f; \
  const int msk = 1; ESH(v0) ESH(v1) }
#define ENTL(l,c) { const float p = sc[192+(l)*15+(c)]; \
  const float pe = ((lane>>((c)-3))&1)?p:0.f; const int msk = 1<<((c)-2); ESH(v0) ESH(v1) }
#define ENT8(l) { const float p = sc[192+(l)*15+8]; \
  const float pe = ((lane>>5)&1)?p:0.f; const int pb = ((wv^1)<<6)|lane; \
  __syncthreads(); xbuf[tid]=v0; xbuf[1024+tid]=v1; __syncthreads(); \
  { float4 o=xbuf[pb];      v0.x+=pe*(o.x-v0.x); v0.y+=pe*(o.y-v0.y); \
                            v0.z+=pe*(o.z-v0.z); v0.w+=pe*(o.w-v0.w); } \
  { float4 o=xbuf[1024+pb]; v1.x+=pe*(o.x-v1.x); v1.y+=pe*(o.y-v1.y); \
                            v1.z+=pe*(o.z-v1.z); v1.w+=pe*(o.w-v1.w); } }
#define ENTW(l,c) { const float p = sc[192+(l)*15+(c)]; const int k=(c)-9; \
  const int cbv = (wv>>k)&1; const int pb = ((wv^(1<<(k+1)))<<6)|lane; \
  __syncthreads(); if(cbv){ xbuf[tid]=v0; xbuf[1024+tid]=v1; } __syncthreads(); \
  if(cbv){ float4 o=xbuf[pb];       v0.x+=p*(o.x-v0.x); v0.y+=p*(o.y-v0.y); \
                                    v0.z+=p*(o.z-v0.z); v0.w+=p*(o.w-v0.w); \
           float4 o1=xbuf[1024+pb]; v1.x+=p*(o1.x-v1.x); v1.y+=p*(o1.y-v1.y); \
                                    v1.z+=p*(o1.z-v1.z); v1.w+=p*(o1.w-v1.w); } }
#define ENT12(l) { const float p = sc[192+(l)*15+12]; const float pe = ((wv>>3)&1)?p:0.f; float d; \
  d=pe*(v0.y-v0.x); v0.x+=d; v0.y-=d;  d=pe*(v0.w-v0.z); v0.z+=d; v0.w-=d; \
  d=pe*(v1.y-v1.x); v1.x+=d; v1.y-=d;  d=pe*(v1.w-v1.z); v1.z+=d; v1.w-=d; }
#define ENT13(l) { const float p = sc[192+(l)*15+13]; float d; \
  d=p*(v0.w-v0.y); v0.y+=d; v0.w-=d;   d=p*(v1.w-v1.y); v1.y+=d; v1.w-=d; }
#define ENT14(l) { const float p = sc[192+(l)*15+14]; float d; \
  d=p*(v1.z-v0.z); v0.z+=d; v1.z-=d;   d=p*(v1.w-v0.w); v0.w+=d; v1.w-=d; }

#define ROTLOC(l) ROTL(l,3) ROTL(l,4) ROTL(l,5) ROTL(l,6) ROTL(l,7) ROTL(l,8) \
  ROTW(l,9) ROTW(l,10) ROTW(l,11) ROTW(l,12) ROT13(l) ROT14(l) ROT15(l)
#define ENTLOC(l) ENT2(l) ENTL(l,3) ENTL(l,4) ENTL(l,5) ENTL(l,6) ENTL(l,7) ENT8(l) \
  ENTW(l,9) ENTW(l,10) ENTW(l,11) ENT12(l) ENT13(l) ENT14(l)

#define GATH(SRC, J, ASSIGN) { \
  const float4* gp = (const float4*)((SRC) + ((J)<<13) + gb); \
  float4 lo = gp[0], hi = gp[1]; \
  float amp = r0*lo.x + r1*lo.y + r2*lo.z + r3*lo.w \
            + r4*hi.x + r5*hi.y + r6*hi.z + r7*hi.w; ASSIGN; }
#define GATHER8(SRC) \
  GATH(SRC,0, v0.x=amp) GATH(SRC,1, v0.y=amp) GATH(SRC,2, v0.z=amp) GATH(SRC,3, v0.w=amp) \
  GATH(SRC,4, v1.x=amp) GATH(SRC,5, v1.y=amp) GATH(SRC,6, v1.z=amp) GATH(SRC,7, v1.w=amp)

#define STORE8(DST) { float* dp = (DST); const int sb = (wv<<9)|(lane<<3)|om; \
  dp[sb + (0<<13)] = v0.x;  dp[sb + (1<<13)] = v0.y; \
  dp[sb + (2<<13)] = v0.z;  dp[sb + (3<<13)] = v0.w; \
  dp[sb + (4<<13)] = v1.x;  dp[sb + (5<<13)] = v1.y; \
  dp[sb + (6<<13)] = v1.z;  dp[sb + (7<<13)] = v1.w; }

__global__ __launch_bounds__(1024) void vqe_coop(
    const float* __restrict__ coords, const float* __restrict__ feats,
    const float* __restrict__ rotp,   const float* __restrict__ entp,
    const float* __restrict__ fpw1,   const float* __restrict__ fpb1,
    const float* __restrict__ fpw2,   const float* __restrict__ fpb2,
    const float* __restrict__ hcw1,   const float* __restrict__ hcb1,
    const float* __restrict__ hcw2,   const float* __restrict__ hcb2,
    const float* __restrict__ hcw3,   const float* __restrict__ hcb3,
    float* __restrict__ out)
{
  cg::grid_group grid = cg::this_grid();
  __shared__ float4 xbuf[2048];       // 32KB wave-exchange buffer
  __shared__ float sc[240];           // rot coefs [0..191] + ent sigmoids [192..236]
  __shared__ float xh[64], fh[64], pf[16];
  __shared__ float h1[256], h2[128], h3[256], ph[1024];

  const int tid = threadIdx.x;
  const int bid = blockIdx.x;
  const int b = bid & 31, om = bid >> 5;
  const int lane = tid & 63, wv = tid >> 6;
  float* realb = out + (size_t)b*OUTSTRIDE;
  float* imagb = realb + NSTATE;

  // ---- stage 0: coefs (all blocks, redundant per octant) + Hamiltonian (om==0) ----
  if (tid < 60) xh[tid] = coords[b*60 + tid];
  if (tid < 64) {
    float acc = fpb1[tid];
    const float* w = fpw1 + tid*100;
    const float* f = feats + b*100;
    for (int k = 0; k < 100; ++k) acc += w[k]*f[k];
    fh[tid] = fmaxf(acc, 0.f);
  } else if (tid < 64+45) {
    sc[192 + (tid-64)] = 1.f/(1.f + expf(-entp[tid-64]));
  }
  __syncthreads();                                    // S1: fh,xh ready
  if (tid < 16) {
    float acc = fpb2[tid];
    const float* w = fpw2 + tid*64;
    for (int k = 0; k < 64; ++k) acc += w[k]*fh[k];
    pf[tid] = tanhf(acc);
  }
  if (om == 0 && tid < 256) {
    float acc = hcb1[tid];
    const float* w = hcw1 + tid*60;
    for (int k = 0; k < 60; ++k) acc += w[k]*xh[k];
    h1[tid] = fmaxf(acc, 0.f);
  }
  __syncthreads();                                    // S2: pf,h1 ready
  if (tid < 48) {                                     // tid = layer*16 + q
    float ang = pf[tid & 15];
    const float* rp = rotp + tid*3;
    float cx = cosf(0.5f*rp[0]*ang), sx = sinf(0.5f*rp[0]*ang);
    float cy = cosf(0.5f*rp[1]*ang), sy = sinf(0.5f*rp[1]*ang);
    float cz = cosf(0.5f*rp[2]*ang), sz = sinf(0.5f*rp[2]*ang);
    float* cc = sc + tid*4;
    cc[0] =  cx*cy*cz; cc[1] = -sx*sy*sz; cc[2] = sx*sy*cz; cc[3] = cx*cy*sz;
  }
  if (om == 0 && tid < 512) {                         // h2 partials (4-way split)
    int o = tid>>2, part = tid&3;
    float s = 0.f;
    const float* w = hcw2 + o*256 + part*64;
    const float* hh = h1 + part*64;
    for (int k = 0; k < 64; ++k) s += w[k]*hh[k];
    ph[tid] = s;
  }
  __syncthreads();                                    // S3: sc complete; ph ready
  if (om == 0) {                                      // block-uniform branch
    if (tid < 128)
      h2[tid] = fmaxf(hcb2[tid] + ph[tid*4]+ph[tid*4+1]+ph[tid*4+2]+ph[tid*4+3], 0.f);
    __syncthreads();
    { int o = tid>>2, part = tid&3;                   // h3 partials (4-way split)
      float s = 0.f;
      const float* w = hcw3 + o*128 + part*32;
      const float* hh = h2 + part*32;
      for (int k = 0; k < 32; ++k) s += w[k]*hh[k];
      ph[tid] = s;
    }
    __syncthreads();
    if (tid < 256)
      h3[tid] = hcb3[tid] + ph[tid*4]+ph[tid*4+1]+ph[tid*4+2]+ph[tid*4+3];
    __syncthreads();
    if (tid < 256) {
      float s = 0.f, sq = 0.f;
      for (int k = 0; k < 60; ++k) { float v = xh[k]; s += v; sq += v*v; }
      float mean = s*(1.f/60.f);
      float var  = (sq - 60.f*mean*mean)*(1.f/59.f);
      float freq = sqrtf(1.f/(var + 1e-6f))*200.f;
      int i = tid >> 4, j = tid & 15;
      out[(size_t)b*OUTSTRIDE + 2*NSTATE + tid] =
          0.5f*(h3[tid] + h3[j*16 + i]) + ((i==j) ? freq : 0.f);
    }
  }

  float4 v0, v1;
  float r0, r1, r2, r3, r4, r5, r6, r7;
  const int gb = (wv<<9) | (lane<<3);

  // ---- phase A: closed-form init + E2-14(0), R3-15(1) -> real ----
  {
    ROWINIT
    // reverse-chron: R1(1) R0(1) E1(0) E0(0) R2(0) R1(0) R0(0)
    RRB(1,1,RB1) RRB(1,0,RB0) REB1(0) REB0(0) RRB(0,2,RB2) RRB(0,1,RB1) RRB(0,0,RB0)
    const float d = r0;                 // row om, column 0 (old state = |0> on bits 0-2)
    float L = 1.f;
    for (int q = 3; q <= 8; ++q) {
      const float* gg = sc + q*4;
      L *= ((lane >> (q-3)) & 1) ? gg[2] : gg[0];
    }
    float W = 1.f;
    for (int q = 9; q <= 12; ++q) {
      const float* gg = sc + q*4;
      W *= ((wv >> (q-9)) & 1) ? gg[2] : gg[0];
    }
    const float base = d * L * W;
    const float a13 = sc[13*4], b13 = sc[13*4+2];
    const float a14 = sc[14*4], b14 = sc[14*4+2];
    const float a15 = sc[15*4], b15 = sc[15*4+2];
    v0.x = base*a13*a14*a15;  v0.y = base*b13*a14*a15;
    v0.z = base*a13*b14*a15;  v0.w = base*b13*b14*a15;
    v1.x = base*a13*a14*b15;  v1.y = base*b13*a14*b15;
    v1.z = base*a13*b14*b15;  v1.w = base*b13*b14*b15;
    ENTLOC(0) ROTLOC(1)
    STORE8(realb)
  }
  __threadfence();
  grid.sync();

  // ---- phase B: gather [R2(1) E01(1) R01(2)] + E2-14(1), R3-15(2) -> imag ----
  {
    ROWINIT
    RRB(2,1,RB1) RRB(2,0,RB0) REB1(1) REB0(1) RRB(1,2,RB2)
    GATHER8(realb)
    ENTLOC(1) ROTLOC(2)
    STORE8(imagb)
  }
  __threadfence();
  grid.sync();

  // ---- phase C: gather [R2(2) E01(2)] + E2-14(2) -> real (final) ----
  {
    ROWINIT
    REB1(2) REB0(2) RRB(2,2,RB2)
    GATHER8(imagb)
    ENTLOC(2)
    STORE8(realb)
  }
  __threadfence();
  grid.sync();

  // ---- tail: zero imag (all phase-C reads of imag are complete) ----
  {
    float4* oz = (float4*)(imagb + om*8192);
    const float4 z = make_float4(0.f, 0.f, 0.f, 0.f);
    oz[tid] = z;
    oz[1024 + tid] = z;
  }
}

extern "C" void kernel_launch(void* const* d_in, const int* in_sizes, int n_in,
                              void* d_out, int out_size, void* d_ws, size_t ws_size,
                              hipStream_t stream) {
  const float* coords = (const float*)d_in[0];
  const float* feats  = (const float*)d_in[1];
  const float* rotp   = (const float*)d_in[2];
  const float* entp   = (const float*)d_in[3];
  const float* fpw1   = (const float*)d_in[4];
  const float* fpb1   = (const float*)d_in[5];
  const float* fpw2   = (const float*)d_in[6];
  const float* fpb2   = (const float*)d_in[7];
  const float* hcw1   = (const float*)d_in[8];
  const float* hcb1   = (const float*)d_in[9];
  const float* hcw2   = (const float*)d_in[10];
  const float* hcb2   = (const float*)d_in[11];
  const float* hcw3   = (const float*)d_in[12];
  const float* hcb3   = (const float*)d_in[13];
  float* out = (float*)d_out;
  void* args[] = {&coords, &feats, &rotp, &entp, &fpw1, &fpb1, &fpw2, &fpb2,
                  &hcw1, &hcb1, &hcw2, &hcb2, &hcw3, &hcb3, &out};
  hipLaunchCooperativeKernel((void*)vqe_coop, dim3(256), dim3(1024),
                             args, 0, stream);
}

// Round 8
// 143.092 us; speedup vs baseline: 4.6106x; 4.6106x over previous
//
#include <hip/hip_runtime.h>
#include <math.h>

#define NSTATE 65536          // 2^16
#define OUTSTRIDE 131328      // 2*65536 + 256

// ============================================================================
// R7 lesson: grid.sync() on 8 XCDs = device-scope L2 writeback+invalidate per
// phase (WRITE_SIZE 25->139MB, 4x regression). Cross-workgroup handoff must be
// a kernel boundary. R6 (6 dispatches, 161us) had only ~6us work/dispatch --
// dead time dominates -> minimize DISPATCH COUNT:
//   kA: coefs (redundant per block) + Ham (om==0) + closed-form layer-0
//       product state + E2-14(0), R3-15(1) -> ws0   [+ zero imag]
//   kB: gather [R2(1) E01(1) R01(2)] from ws0; E2-14(1), R3-15(2) -> ws1
//   kC: gather [R2(2) E01(2)] from ws1; E2-14(2) -> real (final)
// 3 dispatches (big-ws path). Fallback (ws < 16.8MB): A->imag, B->real,
// C->imag, kD copy+zero (4 dispatches).
// Amp index A: bits 0-2 = om (block octant), 3-8 = lane, 9-12 = wave,
// 13-15 = j slot (v0.xyzw,v1.xyzw). b = bid&31 keeps a batch's 8 octant
// blocks on one XCD (round-robin heuristic; perf only) for L2-local gathers.
// All gate math verbatim from R6/R7 (both passed at absmax 4.7e-10).
// ============================================================================

// ---- boundary-row builders (row om of composite 8x8; reverse-chron apply) ----
#define RP(A,B) { float t=A; A = t*g00 + B*g10; B = B*g11 + t*g01; }
#define RB0 RP(r0,r1) RP(r2,r3) RP(r4,r5) RP(r6,r7)
#define RB1 RP(r0,r2) RP(r1,r3) RP(r4,r6) RP(r5,r7)
#define RB2 RP(r0,r4) RP(r1,r5) RP(r2,r6) RP(r3,r7)
#define RRB(l,q,BITS) { const float* gg = sc + ((l)*16+(q))*4; \
  const float g00=gg[0], g01=gg[1], g10=gg[2], g11=gg[3]; BITS }
#define EP(A,B) { float t=A; A = (1.f-p)*A + p*B; B = (1.f-p)*B + p*t; }
#define REB0(l) { const float p = sc[192+(l)*15+0]; EP(r1,r3) EP(r5,r7) }
#define REB1(l) { const float p = sc[192+(l)*15+1]; EP(r2,r6) EP(r3,r7) }
#define ROWINIT r0=(om==0)?1.f:0.f; r1=(om==1)?1.f:0.f; r2=(om==2)?1.f:0.f; \
  r3=(om==3)?1.f:0.f; r4=(om==4)?1.f:0.f; r5=(om==5)?1.f:0.f; \
  r6=(om==6)?1.f:0.f; r7=(om==7)?1.f:0.f;

// ---- local gates (state in v0,v1; sc/xbuf/lane/wv/om/tid in scope) ----
#define SH4(v) { float ox=__shfl_xor(v.x,msk,64), oy=__shfl_xor(v.y,msk,64), \
                       oz=__shfl_xor(v.z,msk,64), ow=__shfl_xor(v.w,msk,64); \
  v.x=cown*v.x+coth*ox; v.y=cown*v.y+coth*oy; v.z=cown*v.z+coth*oz; v.w=cown*v.w+coth*ow; }
#define ROTL(l,q) { const float* gg = sc + ((l)*16+(q))*4; \
  const float g00=gg[0], g01=gg[1], g10=gg[2], g11=gg[3]; \
  const int msk = 1<<((q)-3); const int lb = (lane>>((q)-3))&1; \
  const float cown = lb?g11:g00, coth = lb?g10:g01; SH4(v0) SH4(v1) }
#define ROTW(l,q) { const float* gg = sc + ((l)*16+(q))*4; \
  const float g00=gg[0], g01=gg[1], g10=gg[2], g11=gg[3]; \
  const int k=(q)-9; const int bt=(wv>>k)&1; \
  const float cown = bt?g11:g00, coth = bt?g10:g01; \
  const int pb = ((wv^(1<<k))<<6)|lane; \
  __syncthreads(); xbuf[tid]=v0; xbuf[1024+tid]=v1; __syncthreads(); \
  { float4 o=xbuf[pb];      v0.x=cown*v0.x+coth*o.x; v0.y=cown*v0.y+coth*o.y; \
                            v0.z=cown*v0.z+coth*o.z; v0.w=cown*v0.w+coth*o.w; } \
  { float4 o=xbuf[1024+pb]; v1.x=cown*v1.x+coth*o.x; v1.y=cown*v1.y+coth*o.y; \
                            v1.z=cown*v1.z+coth*o.z; v1.w=cown*v1.w+coth*o.w; } }
#define ROT13(l) { const float* gg = sc + ((l)*16+13)*4; \
  const float g00=gg[0], g01=gg[1], g10=gg[2], g11=gg[3]; float nx,ny,nz,nw; \
  nx=g00*v0.x+g01*v0.y; ny=g10*v0.x+g11*v0.y; nz=g00*v0.z+g01*v0.w; nw=g10*v0.z+g11*v0.w; \
  v0.x=nx; v0.y=ny; v0.z=nz; v0.w=nw; \
  nx=g00*v1.x+g01*v1.y; ny=g10*v1.x+g11*v1.y; nz=g00*v1.z+g01*v1.w; nw=g10*v1.z+g11*v1.w; \
  v1.x=nx; v1.y=ny; v1.z=nz; v1.w=nw; }
#define ROT14(l) { const float* gg = sc + ((l)*16+14)*4; \
  const float g00=gg[0], g01=gg[1], g10=gg[2], g11=gg[3]; float nx,ny,nz,nw; \
  nx=g00*v0.x+g01*v0.z; nz=g10*v0.x+g11*v0.z; ny=g00*v0.y+g01*v0.w; nw=g10*v0.y+g11*v0.w; \
  v0.x=nx; v0.y=ny; v0.z=nz; v0.w=nw; \
  nx=g00*v1.x+g01*v1.z; nz=g10*v1.x+g11*v1.z; ny=g00*v1.y+g01*v1.w; nw=g10*v1.y+g11*v1.w; \
  v1.x=nx; v1.y=ny; v1.z=nz; v1.w=nw; }
#define ROT15(l) { const float* gg = sc + ((l)*16+15)*4; \
  const float g00=gg[0], g01=gg[1], g10=gg[2], g11=gg[3]; float t; \
  t=v0.x; v0.x=g00*t+g01*v1.x; v1.x=g10*t+g11*v1.x; \
  t=v0.y; v0.y=g00*t+g01*v1.y; v1.y=g10*t+g11*v1.y; \
  t=v0.z; v0.z=g00*t+g01*v1.z; v1.z=g10*t+g11*v1.z; \
  t=v0.w; v0.w=g00*t+g01*v1.w; v1.w=g10*t+g11*v1.w; }

#define ESH(v) { float ox=__shfl_xor(v.x,msk,64), oy=__shfl_xor(v.y,msk,64), \
                       oz=__shfl_xor(v.z,msk,64), ow=__shfl_xor(v.w,msk,64); \
  v.x+=pe*(ox-v.x); v.y+=pe*(oy-v.y); v.z+=pe*(oz-v.z); v.w+=pe*(ow-v.w); }
#define ENT2(l) { const float p = sc[192+(l)*15+2]; const float pe = (om&4)?p:0.f; \
  const int msk = 1; ESH(v0) ESH(v1) }
#define ENTL(l,c) { const float p = sc[192+(l)*15+(c)]; \
  const float pe = ((lane>>((c)-3))&1)?p:0.f; const int msk = 1<<((c)-2); ESH(v0) ESH(v1) }
#define ENT8(l) { const float p = sc[192+(l)*15+8]; \
  const float pe = ((lane>>5)&1)?p:0.f; const int pb = ((wv^1)<<6)|lane; \
  __syncthreads(); xbuf[tid]=v0; xbuf[1024+tid]=v1; __syncthreads(); \
  { float4 o=xbuf[pb];      v0.x+=pe*(o.x-v0.x); v0.y+=pe*(o.y-v0.y); \
                            v0.z+=pe*(o.z-v0.z); v0.w+=pe*(o.w-v0.w); } \
  { float4 o=xbuf[1024+pb]; v1.x+=pe*(o.x-v1.x); v1.y+=pe*(o.y-v1.y); \
                            v1.z+=pe*(o.z-v1.z); v1.w+=pe*(o.w-v1.w); } }
#define ENTW(l,c) { const float p = sc[192+(l)*15+(c)]; const int k=(c)-9; \
  const int cbv = (wv>>k)&1; const int pb = ((wv^(1<<(k+1)))<<6)|lane; \
  __syncthreads(); if(cbv){ xbuf[tid]=v0; xbuf[1024+tid]=v1; } __syncthreads(); \
  if(cbv){ float4 o=xbuf[pb];       v0.x+=p*(o.x-v0.x); v0.y+=p*(o.y-v0.y); \
                                    v0.z+=p*(o.z-v0.z); v0.w+=p*(o.w-v0.w); \
           float4 o1=xbuf[1024+pb]; v1.x+=p*(o1.x-v1.x); v1.y+=p*(o1.y-v1.y); \
                                    v1.z+=p*(o1.z-v1.z); v1.w+=p*(o1.w-v1.w); } }
#define ENT12(l) { const float p = sc[192+(l)*15+12]; const float pe = ((wv>>3)&1)?p:0.f; float d; \
  d=pe*(v0.y-v0.x); v0.x+=d; v0.y-=d;  d=pe*(v0.w-v0.z); v0.z+=d; v0.w-=d; \
  d=pe*(v1.y-v1.x); v1.x+=d; v1.y-=d;  d=pe*(v1.w-v1.z); v1.z+=d; v1.w-=d; }
#define ENT13(l) { const float p = sc[192+(l)*15+13]; float d; \
  d=p*(v0.w-v0.y); v0.y+=d; v0.w-=d;   d=p*(v1.w-v1.y); v1.y+=d; v1.w-=d; }
#define ENT14(l) { const float p = sc[192+(l)*15+14]; float d; \
  d=p*(v1.z-v0.z); v0.z+=d; v1.z-=d;   d=p*(v1.w-v0.w); v0.w+=d; v1.w-=d; }

#define ROTLOC(l) ROTL(l,3) ROTL(l,4) ROTL(l,5) ROTL(l,6) ROTL(l,7) ROTL(l,8) \
  ROTW(l,9) ROTW(l,10) ROTW(l,11) ROTW(l,12) ROT13(l) ROT14(l) ROT15(l)
#define ENTLOC(l) ENT2(l) ENTL(l,3) ENTL(l,4) ENTL(l,5) ENTL(l,6) ENTL(l,7) ENT8(l) \
  ENTW(l,9) ENTW(l,10) ENTW(l,11) ENT12(l) ENT13(l) ENT14(l)

#define GATH(SRC, J, ASSIGN) { \
  const float4* gp = (const float4*)((SRC) + ((J)<<13) + gb); \
  float4 lo = gp[0], hi = gp[1]; \
  float amp = r0*lo.x + r1*lo.y + r2*lo.z + r3*lo.w \
            + r4*hi.x + r5*hi.y + r6*hi.z + r7*hi.w; ASSIGN; }
#define GATHER8(SRC) \
  GATH(SRC,0, v0.x=amp) GATH(SRC,1, v0.y=amp) GATH(SRC,2, v0.z=amp) GATH(SRC,3, v0.w=amp) \
  GATH(SRC,4, v1.x=amp) GATH(SRC,5, v1.y=amp) GATH(SRC,6, v1.z=amp) GATH(SRC,7, v1.w=amp)

#define STORE8(DST) { float* dp = (DST); const int sb = (wv<<9)|(lane<<3)|om; \
  dp[sb + (0<<13)] = v0.x;  dp[sb + (1<<13)] = v0.y; \
  dp[sb + (2<<13)] = v0.z;  dp[sb + (3<<13)] = v0.w; \
  dp[sb + (4<<13)] = v1.x;  dp[sb + (5<<13)] = v1.y; \
  dp[sb + (6<<13)] = v1.z;  dp[sb + (7<<13)] = v1.w; }

// coefs into sc[240]: [q*4..] rot r00,r01,r10,r11 per (layer*16+q); [192..236] ent sigmoids
__device__ __forceinline__ void compute_coefs(float* sc, int b, int tid,
    const float* feats, const float* rotp, const float* entp,
    const float* fpw1, const float* fpb1, const float* fpw2, const float* fpb2) {
  __shared__ float fh[64], pf[16];
  if (tid < 64) {
    float acc = fpb1[tid];
    const float* w = fpw1 + tid*100;
    const float* f = feats + b*100;
    for (int k = 0; k < 100; ++k) acc += w[k]*f[k];
    fh[tid] = fmaxf(acc, 0.f);
  } else if (tid < 64+45) {
    sc[192 + (tid-64)] = 1.f/(1.f + expf(-entp[tid-64]));
  }
  __syncthreads();
  if (tid < 16) {
    float acc = fpb2[tid];
    const float* w = fpw2 + tid*64;
    for (int k = 0; k < 64; ++k) acc += w[k]*fh[k];
    pf[tid] = tanhf(acc);
  }
  __syncthreads();
  if (tid < 48) {                       // tid = layer*16 + q
    float ang = pf[tid & 15];
    const float* rp = rotp + tid*3;
    float cx = cosf(0.5f*rp[0]*ang), sx = sinf(0.5f*rp[0]*ang);
    float cy = cosf(0.5f*rp[1]*ang), sy = sinf(0.5f*rp[1]*ang);
    float cz = cosf(0.5f*rp[2]*ang), sz = sinf(0.5f*rp[2]*ang);
    float* cc = sc + tid*4;
    cc[0] =  cx*cy*cz; cc[1] = -sx*sy*sz; cc[2] = sx*sy*cz; cc[3] = cx*cy*sz;
  }
  __syncthreads();
}

// Phase A: coefs + Ham(om==0) + closed-form init + E2-14(0), R3-15(1) -> dst
template<bool ZIMAG>
__global__ __launch_bounds__(1024) void kA(
    const float* __restrict__ coords, const float* __restrict__ feats,
    const float* __restrict__ rotp,   const float* __restrict__ entp,
    const float* __restrict__ fpw1,   const float* __restrict__ fpb1,
    const float* __restrict__ fpw2,   const float* __restrict__ fpb2,
    const float* __restrict__ hcw1,   const float* __restrict__ hcb1,
    const float* __restrict__ hcw2,   const float* __restrict__ hcb2,
    const float* __restrict__ hcw3,   const float* __restrict__ hcb3,
    float* __restrict__ out, float* __restrict__ cws,
    float* __restrict__ dst, int dstride)
{
  __shared__ float4 xbuf[2048];
  __shared__ float sc[240];
  __shared__ float xh[64], h1[256], h2[128], h3[256], ph[1024];
  const int tid = threadIdx.x, bid = blockIdx.x;
  const int b = bid & 31, om = bid >> 5;
  const int lane = tid & 63, wv = tid >> 6;

  compute_coefs(sc, b, tid, feats, rotp, entp, fpw1, fpb1, fpw2, fpb2);
  if (cws != nullptr && om == 0 && tid < 240) cws[b*256 + tid] = sc[tid];

  if (om == 0) {   // block-uniform: Hamiltonian for batch b (verified R7 code)
    if (tid < 60) xh[tid] = coords[b*60 + tid];
    __syncthreads();
    if (tid < 256) {
      float acc = hcb1[tid];
      const float* w = hcw1 + tid*60;
      for (int k = 0; k < 60; ++k) acc += w[k]*xh[k];
      h1[tid] = fmaxf(acc, 0.f);
    }
    __syncthreads();
    if (tid < 512) {                    // h2 partials (4-way split)
      int o = tid>>2, part = tid&3;
      float s = 0.f;
      const float* w = hcw2 + o*256 + part*64;
      const float* hh = h1 + part*64;
      for (int k = 0; k < 64; ++k) s += w[k]*hh[k];
      ph[tid] = s;
    }
    __syncthreads();
    if (tid < 128)
      h2[tid] = fmaxf(hcb2[tid] + ph[tid*4]+ph[tid*4+1]+ph[tid*4+2]+ph[tid*4+3], 0.f);
    __syncthreads();
    { int o = tid>>2, part = tid&3;     // h3 partials (4-way split)
      float s = 0.f;
      const float* w = hcw3 + o*128 + part*32;
      const float* hh = h2 + part*32;
      for (int k = 0; k < 32; ++k) s += w[k]*hh[k];
      ph[tid] = s;
    }
    __syncthreads();
    if (tid < 256)
      h3[tid] = hcb3[tid] + ph[tid*4]+ph[tid*4+1]+ph[tid*4+2]+ph[tid*4+3];
    __syncthreads();
    if (tid < 256) {
      float s = 0.f, sq = 0.f;
      for (int k = 0; k < 60; ++k) { float v = xh[k]; s += v; sq += v*v; }
      float mean = s*(1.f/60.f);
      float var  = (sq - 60.f*mean*mean)*(1.f/59.f);
      float freq = sqrtf(1.f/(var + 1e-6f))*200.f;
      int i = tid >> 4, j = tid & 15;
      out[(size_t)b*OUTSTRIDE + 2*NSTATE + tid] =
          0.5f*(h3[tid] + h3[j*16 + i]) + ((i==j) ? freq : 0.f);
    }
  }

  float4 v0, v1;
  float r0, r1, r2, r3, r4, r5, r6, r7;
  ROWINIT
  // reverse-chron: R1(1) R0(1) E1(0) E0(0) R2(0) R1(0) R0(0)
  RRB(1,1,RB1) RRB(1,0,RB0) REB1(0) REB0(0) RRB(0,2,RB2) RRB(0,1,RB1) RRB(0,0,RB0)
  const float d = r0;                   // row om, column 0 (|0> on bits 0-2)
  float L = 1.f;
  for (int q = 3; q <= 8; ++q) {
    const float* gg = sc + q*4;
    L *= ((lane >> (q-3)) & 1) ? gg[2] : gg[0];
  }
  float W = 1.f;
  for (int q = 9; q <= 12; ++q) {
    const float* gg = sc + q*4;
    W *= ((wv >> (q-9)) & 1) ? gg[2] : gg[0];
  }
  const float base = d * L * W;
  const float a13 = sc[13*4], b13 = sc[13*4+2];
  const float a14 = sc[14*4], b14 = sc[14*4+2];
  const float a15 = sc[15*4], b15 = sc[15*4+2];
  v0.x = base*a13*a14*a15;  v0.y = base*b13*a14*a15;
  v0.z = base*a13*b14*a15;  v0.w = base*b13*b14*a15;
  v1.x = base*a13*a14*b15;  v1.y = base*b13*a14*b15;
  v1.z = base*a13*b14*b15;  v1.w = base*b13*b14*b15;
  ENTLOC(0) ROTLOC(1)
  STORE8(dst + (size_t)b*dstride)

  if constexpr (ZIMAG) {                // imag never touched by sim in ws path
    float4* oz = (float4*)(out + (size_t)b*OUTSTRIDE + NSTATE + om*8192);
    const float4 z = make_float4(0.f, 0.f, 0.f, 0.f);
    oz[tid] = z;
    oz[1024 + tid] = z;
  }
}

// Phase B: gather [R2(1) E01(1) R01(2)] + E2-14(1), R3-15(2)
template<bool LOADC>
__global__ __launch_bounds__(1024) void kB(
    const float* __restrict__ feats, const float* __restrict__ rotp,
    const float* __restrict__ entp,  const float* __restrict__ fpw1,
    const float* __restrict__ fpb1,  const float* __restrict__ fpw2,
    const float* __restrict__ fpb2,  const float* __restrict__ cws,
    const float* __restrict__ src, int sstride,
    float* __restrict__ dst, int dstride)
{
  __shared__ float4 xbuf[2048];
  __shared__ float sc[240];
  const int tid = threadIdx.x, bid = blockIdx.x;
  const int b = bid & 31, om = bid >> 5;
  const int lane = tid & 63, wv = tid >> 6;
  if constexpr (LOADC) {
    for (int i = tid; i < 240; i += 1024) sc[i] = cws[b*256 + i];
    __syncthreads();
  } else {
    compute_coefs(sc, b, tid, feats, rotp, entp, fpw1, fpb1, fpw2, fpb2);
  }
  float4 v0, v1;
  float r0, r1, r2, r3, r4, r5, r6, r7;
  const int gb = (wv<<9) | (lane<<3);
  ROWINIT
  RRB(2,1,RB1) RRB(2,0,RB0) REB1(1) REB0(1) RRB(1,2,RB2)
  GATHER8(src + (size_t)b*sstride)
  ENTLOC(1) ROTLOC(2)
  STORE8(dst + (size_t)b*dstride)
}

// Phase C: gather [R2(2) E01(2)] + E2-14(2) -> final
template<bool LOADC>
__global__ __launch_bounds__(1024) void kC(
    const float* __restrict__ feats, const float* __restrict__ rotp,
    const float* __restrict__ entp,  const float* __restrict__ fpw1,
    const float* __restrict__ fpb1,  const float* __restrict__ fpw2,
    const float* __restrict__ fpb2,  const float* __restrict__ cws,
    const float* __restrict__ src, int sstride,
    float* __restrict__ dst, int dstride)
{
  __shared__ float4 xbuf[2048];
  __shared__ float sc[240];
  const int tid = threadIdx.x, bid = blockIdx.x;
  const int b = bid & 31, om = bid >> 5;
  const int lane = tid & 63, wv = tid >> 6;
  if constexpr (LOADC) {
    for (int i = tid; i < 240; i += 1024) sc[i] = cws[b*256 + i];
    __syncthreads();
  } else {
    compute_coefs(sc, b, tid, feats, rotp, entp, fpw1, fpb1, fpw2, fpb2);
  }
  float4 v0, v1;
  float r0, r1, r2, r3, r4, r5, r6, r7;
  const int gb = (wv<<9) | (lane<<3);
  ROWINIT
  REB1(2) REB0(2) RRB(2,2,RB2)
  GATHER8(src + (size_t)b*sstride)
  ENTLOC(2)
  STORE8(dst + (size_t)b*dstride)
}

// Fallback tail: real <- imag (final state), imag <- 0. Per-(b,om) slices.
__global__ __launch_bounds__(1024) void kD(float* __restrict__ out) {
  const int tid = threadIdx.x, bid = blockIdx.x;
  const int b = bid & 31, om = bid >> 5;
  float4* rr = (float4*)(out + (size_t)b*OUTSTRIDE + om*8192);
  float4* im = (float4*)(out + (size_t)b*OUTSTRIDE + NSTATE + om*8192);
  const float4 z = make_float4(0.f, 0.f, 0.f, 0.f);
  float4 a = im[tid], c = im[1024 + tid];
  rr[tid] = a;  rr[1024 + tid] = c;
  im[tid] = z;  im[1024 + tid] = z;
}

extern "C" void kernel_launch(void* const* d_in, const int* in_sizes, int n_in,
                              void* d_out, int out_size, void* d_ws, size_t ws_size,
                              hipStream_t stream) {
  const float* coords = (const float*)d_in[0];
  const float* feats  = (const float*)d_in[1];
  const float* rotp   = (const float*)d_in[2];
  const float* entp   = (const float*)d_in[3];
  const float* fpw1   = (const float*)d_in[4];
  const float* fpb1   = (const float*)d_in[5];
  const float* fpw2   = (const float*)d_in[6];
  const float* fpb2   = (const float*)d_in[7];
  const float* hcw1   = (const float*)d_in[8];
  const float* hcb1   = (const float*)d_in[9];
  const float* hcw2   = (const float*)d_in[10];
  const float* hcb2   = (const float*)d_in[11];
  const float* hcw3   = (const float*)d_in[12];
  const float* hcb3   = (const float*)d_in[13];
  float* out = (float*)d_out;
  float* wsf = (float*)d_ws;
  const size_t need_big = (size_t)(8192 + 2*32*65536) * 4;   // coef + 2 state bufs

  if (ws_size >= need_big) {
    // 3 dispatches: A -> ws0, B ws0 -> ws1, C ws1 -> real; A zeroes imag.
    float* cws = wsf;
    float* w0 = wsf + 8192;
    float* w1 = w0 + 32*65536;
    kA<true><<<256, 1024, 0, stream>>>(coords, feats, rotp, entp,
        fpw1, fpb1, fpw2, fpb2, hcw1, hcb1, hcw2, hcb2, hcw3, hcb3,
        out, cws, w0, 65536);
    kB<true><<<256, 1024, 0, stream>>>(feats, rotp, entp, fpw1, fpb1, fpw2, fpb2,
        cws, w0, 65536, w1, 65536);
    kC<true><<<256, 1024, 0, stream>>>(feats, rotp, entp, fpw1, fpb1, fpw2, fpb2,
        cws, w1, 65536, out, OUTSTRIDE);
  } else if (ws_size >= 32768) {
    // 4 dispatches: A -> imag, B imag -> real, C real -> imag, D copy+zero.
    float* cws = wsf;
    kA<false><<<256, 1024, 0, stream>>>(coords, feats, rotp, entp,
        fpw1, fpb1, fpw2, fpb2, hcw1, hcb1, hcw2, hcb2, hcw3, hcb3,
        out, cws, out + NSTATE, OUTSTRIDE);
    kB<true><<<256, 1024, 0, stream>>>(feats, rotp, entp, fpw1, fpb1, fpw2, fpb2,
        cws, out + NSTATE, OUTSTRIDE, out, OUTSTRIDE);
    kC<true><<<256, 1024, 0, stream>>>(feats, rotp, entp, fpw1, fpb1, fpw2, fpb2,
        cws, out, OUTSTRIDE, out + NSTATE, OUTSTRIDE);
    kD<<<256, 1024, 0, stream>>>(out);
  } else {
    // tiny ws: recompute coefs in every phase
    kA<false><<<256, 1024, 0, stream>>>(coords, feats, rotp, entp,
        fpw1, fpb1, fpw2, fpb2, hcw1, hcb1, hcw2, hcb2, hcw3, hcb3,
        out, nullptr, out + NSTATE, OUTSTRIDE);
    kB<false><<<256, 1024, 0, stream>>>(feats, rotp, entp, fpw1, fpb1, fpw2, fpb2,
        nullptr, out + NSTATE, OUTSTRIDE, out, OUTSTRIDE);
    kC<false><<<256, 1024, 0, stream>>>(feats, rotp, entp, fpw1, fpb1, fpw2, fpb2,
        nullptr, out, OUTSTRIDE, out + NSTATE, OUTSTRIDE);
    kD<<<256, 1024, 0, stream>>>(out);
  }
}